// Round 3
// baseline (496.429 us; speedup 1.0000x reference)
//
#include <hip/hip_runtime.h>
#include <hip/hip_bf16.h>
#include <cstdint>

// CrossAttention on MI355X — bf16-MFMA pipeline, round 3 resubmit (GPU broker
// at capacity for 3 rounds; kernel desk-checked, never yet executed).
// Shapes fixed by the problem:
#define NB   8
#define NIMG 4096
#define NTXT 512
#define DIMG 512
#define DTXT 768
#define NH   8
#define HD   64
// scale = (TEXT_DIM/H)^-0.5 = 96^-0.5
#define SCALE 0.102062072615966f

typedef __attribute__((ext_vector_type(8))) short  s16x8;   // 8 bf16 (4 VGPR) MFMA A/B frag
typedef __attribute__((ext_vector_type(4))) float  f32x4;   // MFMA C/D frag

union U8 { s16x8 v; unsigned short u[8]; };

__device__ __forceinline__ unsigned short f2bf(float f) {
  unsigned int u = __float_as_uint(f);
  u += 0x7fffu + ((u >> 16) & 1u);           // round-to-nearest-even
  return (unsigned short)(u >> 16);
}

__device__ __forceinline__ s16x8 cvt8(float4 a, float4 b) {
  U8 t;
  t.u[0]=f2bf(a.x); t.u[1]=f2bf(a.y); t.u[2]=f2bf(a.z); t.u[3]=f2bf(a.w);
  t.u[4]=f2bf(b.x); t.u[5]=f2bf(b.y); t.u[6]=f2bf(b.z); t.u[7]=f2bf(b.w);
  return t.v;
}

// ---------------------------------------------------------------------------
// Generic GEMM: C(M,N) = A(M,K) @ W(N,K)^T   (nn.Linear convention)
// AK:  0 = A fp32 (convert on stage), 1 = A bf16
// EPI: 0 = bf16 out, head-split (B,H,NPER,64)
//      1 = bf16 out, head-split TRANSPOSED (B,H,64,NTXT)  (for V^T)
//      2 = fp32 out row-major + bias
// Tile 128x128, BK=64, 4 waves (2x2 of 64x64), 16x16x32 bf16 MFMA.
// LDS tiles XOR-swizzled ((chunk16 ^ (row&7))) -> 2-way conflicts only (free).
// ---------------------------------------------------------------------------
template<int AK, int EPI, int NPER>
__global__ __launch_bounds__(256, 2)
void gemm_k(const void* __restrict__ Ap, const float* __restrict__ W,
            const float* __restrict__ bias, void* __restrict__ Cp,
            const int M, const int N, const int K) {
  __shared__ unsigned short As[128 * 64];
  __shared__ unsigned short Bs[128 * 64];
  const int tid  = threadIdx.x;
  const int lane = tid & 63;
  const int l15  = lane & 15, l4 = lane >> 4;
  const int wid  = tid >> 6;
  const int wm   = (wid >> 1) * 64, wn = (wid & 1) * 64;
  const int m0   = blockIdx.y * 128, n0 = blockIdx.x * 128;

  f32x4 acc[4][4] = {};

  for (int k0 = 0; k0 < K; k0 += 64) {
    __syncthreads();
#pragma unroll
    for (int p = 0; p < 4; ++p) {
      const int q = tid + p * 256;          // 16B-chunk id within 128x64 tile
      const int row = q >> 3, c = q & 7;    // 8 chunks of 8 elems per row
      const int dst = row * 64 + ((c ^ (row & 7)) << 3);
      if constexpr (AK == 0) {
        const float* s = (const float*)Ap + (size_t)(m0 + row) * K + k0 + c * 8;
        float4 f0 = *(const float4*)s;
        float4 f1 = *(const float4*)(s + 4);
        *(s16x8*)&As[dst] = cvt8(f0, f1);
      } else {
        const unsigned short* s = (const unsigned short*)Ap + (size_t)(m0 + row) * K + k0 + c * 8;
        *(s16x8*)&As[dst] = *(const s16x8*)s;
      }
      const float* wsrc = W + (size_t)(n0 + row) * K + k0 + c * 8;
      float4 g0 = *(const float4*)wsrc;
      float4 g1 = *(const float4*)(wsrc + 4);
      *(s16x8*)&Bs[dst] = cvt8(g0, g1);
    }
    __syncthreads();
#pragma unroll
    for (int ks = 0; ks < 2; ++ks) {
      s16x8 af[4], bfr[4];
#pragma unroll
      for (int mf = 0; mf < 4; ++mf) {
        const int row = wm + mf * 16 + l15;
        af[mf] = *(const s16x8*)&As[row * 64 + (((ks * 4 + l4) ^ (row & 7)) << 3)];
      }
#pragma unroll
      for (int nf = 0; nf < 4; ++nf) {
        const int row = wn + nf * 16 + l15;
        bfr[nf] = *(const s16x8*)&Bs[row * 64 + (((ks * 4 + l4) ^ (row & 7)) << 3)];
      }
#pragma unroll
      for (int mf = 0; mf < 4; ++mf)
#pragma unroll
        for (int nf = 0; nf < 4; ++nf)
          acc[mf][nf] = __builtin_amdgcn_mfma_f32_16x16x32_bf16(af[mf], bfr[nf], acc[mf][nf], 0, 0, 0);
    }
  }

  // Epilogue. D layout (verified m89/m91): col = lane&15, row = (lane>>4)*4 + r.
#pragma unroll
  for (int mf = 0; mf < 4; ++mf)
#pragma unroll
    for (int nf = 0; nf < 4; ++nf)
#pragma unroll
      for (int r = 0; r < 4; ++r) {
        const int grow = m0 + wm + mf * 16 + l4 * 4 + r;
        const int gcol = n0 + wn + nf * 16 + l15;
        const float v = acc[mf][nf][r];
        if constexpr (EPI == 2) {
          ((float*)Cp)[(size_t)grow * N + gcol] = v + bias[gcol];
        } else {
          const int bb = grow / NPER, nr = grow % NPER;   // NPER is pow2 template const
          const int hh = gcol >> 6, dd = gcol & 63;
          size_t idx;
          if constexpr (EPI == 0)
            idx = ((size_t)(bb * NH + hh) * NPER + nr) * HD + dd;
          else
            idx = ((size_t)(bb * NH + hh) * HD + dd) * NTXT + nr;  // V^T
          ((unsigned short*)Cp)[idx] = f2bf(v);
        }
      }
}

// ---------------------------------------------------------------------------
// Flash attention: block = 128 Q-rows for one (b,h); 4 waves x 32 rows.
// K/V fragments loaded straight from global (K+V per (b,h) = 128 KB, L2-hot,
// shared by 32 consecutive blocks). V is pre-transposed so the PV B-operand
// is contiguous. P goes through per-wave swizzled LDS (D-layout -> A-layout).
// ---------------------------------------------------------------------------
__global__ __launch_bounds__(256, 2)
void attn_k(const unsigned short* __restrict__ Qbf,   // (B,H,4096,64)
            const unsigned short* __restrict__ Kbf,   // (B,H,512,64)
            const unsigned short* __restrict__ Vt,    // (B,H,64,512)
            const int* __restrict__ msk,              // (B,512)
            unsigned short* __restrict__ Abf) {       // (B,4096,512)
  __shared__ unsigned short Plds[4][32 * 64];
  const int blk = blockIdx.x;
  const int qt = blk & 31, bh = blk >> 5;
  const int b = bh >> 3, h = bh & 7;
  const int tid = threadIdx.x, lane = tid & 63, w = tid >> 6;
  const int l15 = lane & 15, l4 = lane >> 4;

  const unsigned short* Qb = Qbf + (size_t)bh * NIMG * HD;
  const unsigned short* Kb = Kbf + (size_t)bh * NTXT * HD;
  const unsigned short* Vb = Vt  + (size_t)bh * HD * NTXT;
  const int* mb = msk + b * NTXT;

  const int qrow0 = qt * 128 + w * 32;

  // Q fragments in registers: 32 rows x 64 (2 mfrag x 2 kslab)
  s16x8 aq[2][2];
#pragma unroll
  for (int mf = 0; mf < 2; ++mf)
#pragma unroll
    for (int ks = 0; ks < 2; ++ks)
      aq[mf][ks] = *(const s16x8*)(Qb + (size_t)(qrow0 + mf * 16 + l15) * HD + ks * 32 + l4 * 8);

  f32x4 o[2][4] = {};
  float mst[2][4], lst[2][4];
#pragma unroll
  for (int mf = 0; mf < 2; ++mf)
#pragma unroll
    for (int r = 0; r < 4; ++r) { mst[mf][r] = -1e30f; lst[mf][r] = 0.f; }

  for (int t = 0; t < 8; ++t) {
    const int j0 = t * 64;
    // K fragments (B operand of QK^T): row = kv index, contiguous k
    s16x8 bk[4][2];
#pragma unroll
    for (int nf = 0; nf < 4; ++nf)
#pragma unroll
      for (int ks = 0; ks < 2; ++ks)
        bk[nf][ks] = *(const s16x8*)(Kb + (size_t)(j0 + nf * 16 + l15) * HD + ks * 32 + l4 * 8);

    f32x4 s[2][4] = {};
#pragma unroll
    for (int ks = 0; ks < 2; ++ks)
#pragma unroll
      for (int mf = 0; mf < 2; ++mf)
#pragma unroll
        for (int nf = 0; nf < 4; ++nf)
          s[mf][nf] = __builtin_amdgcn_mfma_f32_16x16x32_bf16(aq[mf][ks], bk[nf][ks], s[mf][nf], 0, 0, 0);

    float madd[4];
#pragma unroll
    for (int nf = 0; nf < 4; ++nf)
      madd[nf] = mb[j0 + nf * 16 + l15] ? 0.f : -1e30f;

#pragma unroll
    for (int mf = 0; mf < 2; ++mf) {
      float nm[4];
#pragma unroll
      for (int r = 0; r < 4; ++r) {
        float x = -1e30f;
#pragma unroll
        for (int nf = 0; nf < 4; ++nf) {
          const float sv = s[mf][nf][r] * SCALE + madd[nf];
          s[mf][nf][r] = sv;
          x = fmaxf(x, sv);
        }
        nm[r] = x;
      }
      // row-max across the 16 lanes holding this row's 64 columns
#pragma unroll
      for (int d = 1; d < 16; d <<= 1)
#pragma unroll
        for (int r = 0; r < 4; ++r) nm[r] = fmaxf(nm[r], __shfl_xor(nm[r], d));

      float psum[4] = {0.f, 0.f, 0.f, 0.f};
#pragma unroll
      for (int r = 0; r < 4; ++r) {
        const float mn = fmaxf(mst[mf][r], nm[r]);
        const float alpha = __expf(mst[mf][r] - mn);
        mst[mf][r] = mn;
        lst[mf][r] *= alpha;
#pragma unroll
        for (int hf = 0; hf < 4; ++hf) o[mf][hf][r] *= alpha;
      }
#pragma unroll
      for (int nf = 0; nf < 4; ++nf)
#pragma unroll
        for (int r = 0; r < 4; ++r) {
          const float p = __expf(s[mf][nf][r] - mst[mf][r]);
          s[mf][nf][r] = p;
          psum[r] += p;
        }
#pragma unroll
      for (int d = 1; d < 16; d <<= 1)
#pragma unroll
        for (int r = 0; r < 4; ++r) psum[r] += __shfl_xor(psum[r], d);
#pragma unroll
      for (int r = 0; r < 4; ++r) lst[mf][r] += psum[r];

      // P (D-layout) -> per-wave swizzled LDS (bf16)
#pragma unroll
      for (int nf = 0; nf < 4; ++nf)
#pragma unroll
        for (int r = 0; r < 4; ++r) {
          const int prow = mf * 16 + l4 * 4 + r;
          const int pcol = nf * 16 + l15;
          const int off = prow * 64 + (((pcol >> 3) ^ (prow & 7)) << 3) + (pcol & 7);
          Plds[w][off] = f2bf(s[mf][nf][r]);
        }
    }
    asm volatile("s_waitcnt lgkmcnt(0)" ::: "memory");
    __builtin_amdgcn_sched_barrier(0);

    // PV: O[i][d] += P[i][j] * V[j][d];  B-frag from V^T is contiguous
    s16x8 bv[4][2];
#pragma unroll
    for (int hf = 0; hf < 4; ++hf)
#pragma unroll
      for (int ks = 0; ks < 2; ++ks)
        bv[hf][ks] = *(const s16x8*)(Vb + (size_t)(hf * 16 + l15) * NTXT + j0 + ks * 32 + l4 * 8);

#pragma unroll
    for (int mf = 0; mf < 2; ++mf) {
      s16x8 pa[2];
#pragma unroll
      for (int ks = 0; ks < 2; ++ks) {
        const int row = mf * 16 + l15;
        pa[ks] = *(const s16x8*)&Plds[w][row * 64 + (((ks * 4 + l4) ^ (row & 7)) << 3)];
      }
#pragma unroll
      for (int hf = 0; hf < 4; ++hf)
#pragma unroll
        for (int ks = 0; ks < 2; ++ks)
          o[mf][hf] = __builtin_amdgcn_mfma_f32_16x16x32_bf16(pa[ks], bv[hf][ks], o[mf][hf], 0, 0, 0);
    }
  }

  // epilogue: divide by row-sum, write attended (B,4096,512) head-interleaved
#pragma unroll
  for (int mf = 0; mf < 2; ++mf) {
    float rl[4];
#pragma unroll
    for (int r = 0; r < 4; ++r) rl[r] = 1.f / lst[mf][r];
#pragma unroll
    for (int hf = 0; hf < 4; ++hf)
#pragma unroll
      for (int r = 0; r < 4; ++r) {
        const int qrow = qrow0 + mf * 16 + l4 * 4 + r;
        const int col = h * 64 + hf * 16 + l15;
        Abf[((size_t)b * NIMG + qrow) * DIMG + col] = f2bf(o[mf][hf][r] * rl[r]);
      }
  }
}

// ---------------------------------------------------------------------------
extern "C" void kernel_launch(void* const* d_in, const int* in_sizes, int n_in,
                              void* d_out, int out_size, void* d_ws, size_t ws_size,
                              hipStream_t stream) {
  const float* img  = (const float*)d_in[0];
  const float* txt  = (const float*)d_in[1];
  const int*   mask = (const int*)d_in[2];
  const float* Wq   = (const float*)d_in[3];
  const float* Wk   = (const float*)d_in[4];
  const float* Wv   = (const float*)d_in[5];
  const float* Wo   = (const float*)d_in[6];
  const float* bo   = (const float*)d_in[7];
  float* out = (float*)d_out;

  char* ws = (char*)d_ws;
  unsigned short* Qbf = (unsigned short*)ws;                               // 32 MB (B,H,4096,64)
  unsigned short* Kbf = (unsigned short*)(ws + (size_t)NB*NH*NIMG*HD*2);   //  4 MB (B,H,512,64)
  unsigned short* Vtw = Kbf + (size_t)NB*NH*NTXT*HD;                       //  4 MB (B,H,64,512)
  unsigned short* Abf = Vtw + (size_t)NB*NH*HD*NTXT;                       // 32 MB (B,4096,512)

  // Q = img @ Wq^T   (32768 x 512 x 512)
  gemm_k<0, 0, NIMG><<<dim3(4, 256), 256, 0, stream>>>(img, Wq, nullptr, Qbf, NB*NIMG, DIMG, DIMG);
  // K = txt @ Wk^T   (4096 x 512 x 768)
  gemm_k<0, 0, NTXT><<<dim3(4, 32), 256, 0, stream>>>(txt, Wk, nullptr, Kbf, NB*NTXT, DIMG, DTXT);
  // V^T = (txt @ Wv^T)^T
  gemm_k<0, 1, NTXT><<<dim3(4, 32), 256, 0, stream>>>(txt, Wv, nullptr, Vtw, NB*NTXT, DIMG, DTXT);
  // attention
  attn_k<<<dim3(NB*NH*(NIMG/128)), 256, 0, stream>>>(Qbf, Kbf, Vtw, mask, Abf);
  // out = attended @ Wo^T + bo   (32768 x 512 x 512), fp32
  gemm_k<1, 2, 1><<<dim3(4, 256), 256, 0, stream>>>(Abf, Wo, bo, out, NB*NIMG, DIMG, DIMG);
}

// Round 5
// 377.484 us; speedup vs baseline: 1.3151x; 1.3151x over previous
//
#include <hip/hip_runtime.h>
#include <hip/hip_bf16.h>
#include <cstdint>

// CrossAttention on MI355X — round 5.
// Round-4 bug fix: swapped-QK^T attn rescaled O with the WRONG row's
// softmax state (lane state is per q=l15, O-frag rows are q=l4*4+r).
// Fix: shuffle alpha / 1/lst from lane (lane&48)|(l4*4+r) before applying.
// GEMM structure (gld16 m97-style), fused KV, P-LDS path: unchanged from r4.
#define NB   8
#define NIMG 4096
#define NTXT 512
#define DIMG 512
#define DTXT 768
#define NH   8
#define HD   64
#define SCALE 0.102062072615966f

typedef __attribute__((ext_vector_type(8))) short          s16x8;
typedef __attribute__((ext_vector_type(4))) unsigned short u16x4;
typedef __attribute__((ext_vector_type(4))) float          f32x4;
typedef unsigned short u16;
typedef unsigned int   u32;

union U8 { s16x8 v; u16 u[8]; };

__device__ __forceinline__ u16 f2bf(float f) {
  u32 u = __float_as_uint(f);
  u += 0x7fffu + ((u >> 16) & 1u);           // round-to-nearest-even
  return (u16)(u >> 16);
}
__device__ __forceinline__ s16x8 cvt8(float4 a, float4 b) {
  U8 t;
  t.u[0]=f2bf(a.x); t.u[1]=f2bf(a.y); t.u[2]=f2bf(a.z); t.u[3]=f2bf(a.w);
  t.u[4]=f2bf(b.x); t.u[5]=f2bf(b.y); t.u[6]=f2bf(b.z); t.u[7]=f2bf(b.w);
  return t.v;
}

// ---------------------------------------------------------------------------
// fp32 -> bf16 bulk convert, vectorized (32B in / 16B out per iter)
// ---------------------------------------------------------------------------
__global__ void convk(const float* __restrict__ in, u16* __restrict__ out, int n8) {
  int i = blockIdx.x * 256 + threadIdx.x;
  const int stride = gridDim.x * 256;
  for (; i < n8; i += stride) {
    float4 a = ((const float4*)in)[2 * i];
    float4 b = ((const float4*)in)[2 * i + 1];
    ((s16x8*)out)[i] = cvt8(a, b);
  }
}

// async global->LDS, 16B per lane; LDS dest = wave-uniform base + lane*16
__device__ __forceinline__ void gld16(const u16* g, u16* l) {
  __builtin_amdgcn_global_load_lds((const __attribute__((address_space(1))) u32*)g,
                                   (__attribute__((address_space(3))) u32*)l, 16, 0, 0);
}

// ---------------------------------------------------------------------------
// bf16 GEMM (m97 structure): C(M,N) = A(M,K) @ W(N,K)^T
// global_load_lds width16, linear LDS dest, PRE-SWIZZLED global source,
// swizzled ds_read_b128 (both-sides-or-neither, rule #21).
// EPI 0: bf16 head-split (B,H,NPER,64);  EPI 2: fp32 + bias
// ---------------------------------------------------------------------------
template<int EPI, int NPER>
__global__ __launch_bounds__(256, 2)
void gemm_bf(const u16* __restrict__ A, const u16* __restrict__ W,
             const float* __restrict__ bias, void* __restrict__ Cp,
             const int N, const int K) {
  __shared__ u16 As[128 * 64];
  __shared__ u16 Bs[128 * 64];
  const int tid = threadIdx.x, lane = tid & 63, w = tid >> 6;
  const int l15 = lane & 15, l4 = lane >> 4;
  const int wm = (w >> 1) * 64, wn = (w & 1) * 64;
  const int m0 = blockIdx.y * 128, n0 = blockIdx.x * 128;
  const int srow = lane >> 3, schk = lane & 7;    // staging row-in-group / chunk

  f32x4 acc[4][4] = {};

  for (int k0 = 0; k0 < K; k0 += 64) {
    __syncthreads();
#pragma unroll
    for (int i = 0; i < 4; ++i) {
      const int rg  = (w * 4 + i) * 8;            // 8-row group base
      const int row = rg + srow;
      const int sc  = schk ^ (row & 7);           // pre-swizzled source chunk
      gld16(A + (size_t)(m0 + row) * K + k0 + sc * 8, &As[rg * 64]);
      gld16(W + (size_t)(n0 + row) * K + k0 + sc * 8, &Bs[rg * 64]);
    }
    __syncthreads();                               // drains vmcnt (compiler)
#pragma unroll
    for (int ks = 0; ks < 2; ++ks) {
      s16x8 af[4], bw[4];
#pragma unroll
      for (int mf = 0; mf < 4; ++mf) {
        const int row = wm + mf * 16 + l15;
        af[mf] = *(const s16x8*)&As[row * 64 + (((ks * 4 + l4) ^ (row & 7)) << 3)];
      }
#pragma unroll
      for (int nf = 0; nf < 4; ++nf) {
        const int row = wn + nf * 16 + l15;
        bw[nf] = *(const s16x8*)&Bs[row * 64 + (((ks * 4 + l4) ^ (row & 7)) << 3)];
      }
#pragma unroll
      for (int mf = 0; mf < 4; ++mf)
#pragma unroll
        for (int nf = 0; nf < 4; ++nf)
          acc[mf][nf] = __builtin_amdgcn_mfma_f32_16x16x32_bf16(af[mf], bw[nf], acc[mf][nf], 0, 0, 0);
    }
  }

#pragma unroll
  for (int mf = 0; mf < 4; ++mf)
#pragma unroll
    for (int nf = 0; nf < 4; ++nf)
#pragma unroll
      for (int r = 0; r < 4; ++r) {
        const int grow = m0 + wm + mf * 16 + l4 * 4 + r;
        const int gcol = n0 + wn + nf * 16 + l15;
        const float v = acc[mf][nf][r];
        if constexpr (EPI == 2) {
          ((float*)Cp)[(size_t)grow * N + gcol] = v + bias[gcol];
        } else {
          const int bb = grow / NPER, nr = grow % NPER;
          const int hh = gcol >> 6, dd = gcol & 63;
          ((u16*)Cp)[((size_t)(bb * NH + hh) * NPER + nr) * HD + dd] = f2bf(v);
        }
      }
}

// ---------------------------------------------------------------------------
// K+V projection in one kernel (fp32 inputs, proven cvt-staging path).
// blockIdx.x 0-3 -> K columns (Kbf layout), 4-7 -> V columns (V^T layout).
// ---------------------------------------------------------------------------
__global__ __launch_bounds__(256, 2)
void gemm_kv(const float* __restrict__ txt, const float* __restrict__ Wk,
             const float* __restrict__ Wv, u16* __restrict__ Kbf,
             u16* __restrict__ Vtw) {
  constexpr int K = DTXT;
  __shared__ u16 As[128 * 64];
  __shared__ u16 Bs[128 * 64];
  const int tid = threadIdx.x, lane = tid & 63, w = tid >> 6;
  const int l15 = lane & 15, l4 = lane >> 4;
  const int wm = (w >> 1) * 64, wn = (w & 1) * 64;
  const float* W = (blockIdx.x < 4) ? Wk : Wv;
  const int n0 = (blockIdx.x & 3) * 128;
  const int m0 = blockIdx.y * 128;

  f32x4 acc[4][4] = {};

  for (int k0 = 0; k0 < K; k0 += 64) {
    __syncthreads();
#pragma unroll
    for (int p = 0; p < 4; ++p) {
      const int q = tid + p * 256;
      const int row = q >> 3, c = q & 7;
      const int dst = row * 64 + ((c ^ (row & 7)) << 3);
      const float* sa = txt + (size_t)(m0 + row) * K + k0 + c * 8;
      *(s16x8*)&As[dst] = cvt8(*(const float4*)sa, *(const float4*)(sa + 4));
      const float* sw = W + (size_t)(n0 + row) * K + k0 + c * 8;
      *(s16x8*)&Bs[dst] = cvt8(*(const float4*)sw, *(const float4*)(sw + 4));
    }
    __syncthreads();
#pragma unroll
    for (int ks = 0; ks < 2; ++ks) {
      s16x8 af[4], bw[4];
#pragma unroll
      for (int mf = 0; mf < 4; ++mf) {
        const int row = wm + mf * 16 + l15;
        af[mf] = *(const s16x8*)&As[row * 64 + (((ks * 4 + l4) ^ (row & 7)) << 3)];
      }
#pragma unroll
      for (int nf = 0; nf < 4; ++nf) {
        const int row = wn + nf * 16 + l15;
        bw[nf] = *(const s16x8*)&Bs[row * 64 + (((ks * 4 + l4) ^ (row & 7)) << 3)];
      }
#pragma unroll
      for (int mf = 0; mf < 4; ++mf)
#pragma unroll
        for (int nf = 0; nf < 4; ++nf)
          acc[mf][nf] = __builtin_amdgcn_mfma_f32_16x16x32_bf16(af[mf], bw[nf], acc[mf][nf], 0, 0, 0);
    }
  }

#pragma unroll
  for (int mf = 0; mf < 4; ++mf)
#pragma unroll
    for (int nf = 0; nf < 4; ++nf)
#pragma unroll
      for (int r = 0; r < 4; ++r) {
        const int grow = m0 + wm + mf * 16 + l4 * 4 + r;   // 0..4095
        const int gcol = n0 + wn + nf * 16 + l15;          // 0..511
        const int bb = grow >> 9, nr = grow & 511;
        const int hh = gcol >> 6, dd = gcol & 63;
        const u16 v = f2bf(acc[mf][nf][r]);
        if (blockIdx.x < 4)
          Kbf[((size_t)(bb * NH + hh) * NTXT + nr) * HD + dd] = v;
        else
          Vtw[((size_t)(bb * NH + hh) * HD + dd) * NTXT + nr] = v;
      }
}

// ---------------------------------------------------------------------------
// Flash attention, swapped QK^T (S^T = K*Q^T). Block = 128 q-rows, 4 waves.
// Lane softmax state is per q = l15; O-frag rows are q = l4*4+r, so alpha
// and 1/lst are SHUFFLED from lane (lane&48)|(l4*4+r) before applying (the
// round-4 bug was applying the l15 row's state directly).
// ---------------------------------------------------------------------------
__global__ __launch_bounds__(256, 2)
void attn_k(const u16* __restrict__ Qbf,   // (B,H,4096,64)
            const u16* __restrict__ Kbf,   // (B,H,512,64)
            const u16* __restrict__ Vt,    // (B,H,64,512)
            const int* __restrict__ msk,   // (B,512)
            u16* __restrict__ Abf) {       // (B,4096,512)
  __shared__ u16 Plds[4][32 * 64];
  const int blk = blockIdx.x;
  const int qt = blk & 31, bh = blk >> 5;
  const int b = bh >> 3, h = bh & 7;
  const int tid = threadIdx.x, lane = tid & 63, w = tid >> 6;
  const int l15 = lane & 15, l4 = lane >> 4;
  const int sbase = lane & 48;             // lane group base for row-state shfl

  const u16* Qb = Qbf + (size_t)bh * NIMG * HD;
  const u16* Kb = Kbf + (size_t)bh * NTXT * HD;
  const u16* Vb = Vt  + (size_t)bh * HD * NTXT;
  const int* mb = msk + b * NTXT;
  const int qrow0 = qt * 128 + w * 32;

  // Q as B-operand frags: lane holds Q[qrow0+nfq*16+l15][ks*32+l4*8 ..+7]
  s16x8 aq[2][2];
#pragma unroll
  for (int nfq = 0; nfq < 2; ++nfq)
#pragma unroll
    for (int ks = 0; ks < 2; ++ks)
      aq[nfq][ks] = *(const s16x8*)(Qb + (size_t)(qrow0 + nfq * 16 + l15) * HD + ks * 32 + l4 * 8);

  f32x4 o[2][4] = {};
  float mst[2] = {-1e30f, -1e30f}, lst[2] = {0.f, 0.f};

  for (int t = 0; t < 8; ++t) {
    const int j0 = t * 64;
    // K as A-operand frags
    s16x8 bk[4][2];
#pragma unroll
    for (int mfk = 0; mfk < 4; ++mfk)
#pragma unroll
      for (int ks = 0; ks < 2; ++ks)
        bk[mfk][ks] = *(const s16x8*)(Kb + (size_t)(j0 + mfk * 16 + l15) * HD + ks * 32 + l4 * 8);

    // S^T[kv][q]
    f32x4 st[4][2] = {};
#pragma unroll
    for (int ks = 0; ks < 2; ++ks)
#pragma unroll
      for (int mfk = 0; mfk < 4; ++mfk)
#pragma unroll
        for (int nfq = 0; nfq < 2; ++nfq)
          st[mfk][nfq] = __builtin_amdgcn_mfma_f32_16x16x32_bf16(bk[mfk][ks], aq[nfq][ks], st[mfk][nfq], 0, 0, 0);

    // V frags issued early: latency hides under softmax
    s16x8 bv[4][2];
#pragma unroll
    for (int hf = 0; hf < 4; ++hf)
#pragma unroll
      for (int ks = 0; ks < 2; ++ks)
        bv[hf][ks] = *(const s16x8*)(Vb + (size_t)(hf * 16 + l15) * NTXT + j0 + ks * 32 + l4 * 8);

    // mask addend for this lane's kv set: kv = mfk*16 + l4*4 + r
    float madd[4][4];
#pragma unroll
    for (int mfk = 0; mfk < 4; ++mfk) {
      const int4 mm = *(const int4*)(mb + j0 + mfk * 16 + l4 * 4);
      madd[mfk][0] = mm.x ? 0.f : -1e30f;
      madd[mfk][1] = mm.y ? 0.f : -1e30f;
      madd[mfk][2] = mm.z ? 0.f : -1e30f;
      madd[mfk][3] = mm.w ? 0.f : -1e30f;
    }

#pragma unroll
    for (int nfq = 0; nfq < 2; ++nfq) {
      float nm = -1e30f;
#pragma unroll
      for (int mfk = 0; mfk < 4; ++mfk)
#pragma unroll
        for (int r = 0; r < 4; ++r) {
          const float sv = st[mfk][nfq][r] * SCALE + madd[mfk][r];
          st[mfk][nfq][r] = sv;
          nm = fmaxf(nm, sv);
        }
      nm = fmaxf(nm, __shfl_xor(nm, 16));
      nm = fmaxf(nm, __shfl_xor(nm, 32));
      const float mn = fmaxf(mst[nfq], nm);
      const float alpha = __expf(mst[nfq] - mn);
      mst[nfq] = mn;
      float ps = 0.f;
#pragma unroll
      for (int mfk = 0; mfk < 4; ++mfk)
#pragma unroll
        for (int r = 0; r < 4; ++r) {
          const float p = __expf(st[mfk][nfq][r] - mn);
          st[mfk][nfq][r] = p;
          ps += p;
        }
      ps += __shfl_xor(ps, 16);
      ps += __shfl_xor(ps, 32);
      lst[nfq] = lst[nfq] * alpha + ps;

      // FIX (r4 bug): o rows are q = nfq*16 + l4*4 + r — fetch each row's
      // alpha from the lane (same l4 group, l15 = l4*4+r) that owns it.
      float ar[4];
#pragma unroll
      for (int r = 0; r < 4; ++r) ar[r] = __shfl(alpha, sbase + l4 * 4 + r);
#pragma unroll
      for (int hf = 0; hf < 4; ++hf)
#pragma unroll
        for (int r = 0; r < 4; ++r) o[nfq][hf][r] *= ar[r];

      // P[q][kv] -> LDS, b64 writes, 8B-chunk XOR swizzle (q = l15 row: OK)
      const int q = nfq * 16 + l15;
      const int E = (q & 7) << 1;
#pragma unroll
      for (int mfk = 0; mfk < 4; ++mfk) {
        u16x4 pk;
        pk[0] = f2bf(st[mfk][nfq][0]); pk[1] = f2bf(st[mfk][nfq][1]);
        pk[2] = f2bf(st[mfk][nfq][2]); pk[3] = f2bf(st[mfk][nfq][3]);
        const int c8 = mfk * 4 + l4;
        *(u16x4*)((char*)&Plds[w][0] + q * 128 + (((c8) ^ E) << 3)) = pk;
      }
    }
    asm volatile("" ::: "memory");   // compiler ordering barrier (no runtime cost)

    // PV: O[q][d] += P[q][kv] * V[kv][d]
#pragma unroll
    for (int mfq = 0; mfq < 2; ++mfq) {
      const int q = mfq * 16 + l15;
      const int E = (q & 7) << 1;
      s16x8 pa[2];
#pragma unroll
      for (int ks = 0; ks < 2; ++ks)
        pa[ks] = *(const s16x8*)((const char*)&Plds[w][0] + q * 128 + (((ks * 8 + l4 * 2) ^ E) << 3));
#pragma unroll
      for (int hf = 0; hf < 4; ++hf)
#pragma unroll
        for (int ks = 0; ks < 2; ++ks)
          o[mfq][hf] = __builtin_amdgcn_mfma_f32_16x16x32_bf16(pa[ks], bv[hf][ks], o[mfq][hf], 0, 0, 0);
    }
  }

  // epilogue — same row-state shuffle for 1/lst (r4 bug fix)
#pragma unroll
  for (int nfq = 0; nfq < 2; ++nfq) {
    const float rl = 1.f / lst[nfq];
    float rr[4];
#pragma unroll
    for (int r = 0; r < 4; ++r) rr[r] = __shfl(rl, sbase + l4 * 4 + r);
#pragma unroll
    for (int hf = 0; hf < 4; ++hf)
#pragma unroll
      for (int r = 0; r < 4; ++r) {
        const int qrow = qrow0 + nfq * 16 + l4 * 4 + r;
        const int col = h * 64 + hf * 16 + l15;
        Abf[((size_t)b * NIMG + qrow) * DIMG + col] = f2bf(o[nfq][hf][r] * rr[r]);
      }
  }
}

// ---------------------------------------------------------------------------
extern "C" void kernel_launch(void* const* d_in, const int* in_sizes, int n_in,
                              void* d_out, int out_size, void* d_ws, size_t ws_size,
                              hipStream_t stream) {
  const float* img  = (const float*)d_in[0];
  const float* txt  = (const float*)d_in[1];
  const int*   mask = (const int*)d_in[2];
  const float* Wq   = (const float*)d_in[3];
  const float* Wk   = (const float*)d_in[4];
  const float* Wv   = (const float*)d_in[5];
  const float* Wo   = (const float*)d_in[6];
  const float* bo   = (const float*)d_in[7];
  float* out = (float*)d_out;

  char* ws = (char*)d_ws;
  u16* imgBf = (u16*)ws;                        // 33.55 MB; reused as Abf after Q-proj
  u16* Qbf   = (u16*)(ws + 33554432);           // 33.55 MB
  u16* Kbf   = (u16*)(ws + 67108864);           //  4.19 MB
  u16* Vtw   = (u16*)(ws + 71303168);           //  4.19 MB
  u16* WqBf  = (u16*)(ws + 75497472);           //  0.52 MB
  u16* WoBf  = (u16*)(ws + 76021760);           //  0.52 MB  (total 76.5 MB)

  convk<<<2048, 256, 0, stream>>>(img, imgBf, NB * NIMG * DIMG / 8);
  convk<<<128,  256, 0, stream>>>(Wq, WqBf, DIMG * DIMG / 8);
  convk<<<128,  256, 0, stream>>>(Wo, WoBf, DIMG * DIMG / 8);

  // Q = img @ Wq^T  (32768 x 512 x 512), head-split bf16
  gemm_bf<0, NIMG><<<dim3(4, 256), 256, 0, stream>>>(imgBf, WqBf, nullptr, Qbf, DIMG, DIMG);
  // K, V^T = txt @ {Wk,Wv}^T  (4096 x 512 x 768), 256 blocks
  gemm_kv<<<dim3(8, 32), 256, 0, stream>>>(txt, Wk, Wv, Kbf, Vtw);
  // attention -> Abf (overwrites imgBf; img dead after Q-proj)
  attn_k<<<dim3(NB * NH * (NIMG / 128)), 256, 0, stream>>>(Qbf, Kbf, Vtw, mask, imgBf);
  // out = attended @ Wo^T + bo  (32768 x 512 x 512), fp32
  gemm_bf<2, 1><<<dim3(4, 256), 256, 0, stream>>>(imgBf, WoBf, bo, out, DIMG, DIMG);
}